// Round 10
// baseline (185.246 us; speedup 1.0000x reference)
//
#include <hip/hip_runtime.h>

#define B_ 4
#define C_ 256
#define HH 64
#define WW 64
#define N_ 4096
#define IC_ 128
#define JC_ 8   // j-split factor for correlation (R3 locality regime)

typedef __attribute__((ext_vector_type(8))) short bf16x8;
typedef __attribute__((ext_vector_type(4))) float f32x4;

__device__ __forceinline__ short f2bf(float f) {
    unsigned u = __builtin_bit_cast(unsigned, f);
    unsigned r = (u + 0x7FFFu + ((u >> 16) & 1u)) >> 16;
    return (short)r;
}

__device__ __forceinline__ int refl(int v) {
    return v < 0 ? -v : (v > 63 ? 126 - v : v);
}

// ---------------- K0: convert projection weights to bf16 ----------------
__global__ __launch_bounds__(256) void k_cvt_w(const float* __restrict__ wt,
                                               const float* __restrict__ wp,
                                               short* __restrict__ wtb,
                                               short* __restrict__ wpb) {
    int i = blockIdx.x * 256 + threadIdx.x;  // 32768 total
    wtb[i] = f2bf(wt[i]);
    wpb[i] = f2bf(wp[i]);
}

// ---------------- K1: projection GEMM (MFMA) -> thetaT/phiT [B][N][IC] bf16 ----
// n-tile 32/block, waves split ic (2 cf each): 1024 blocks = 4/CU, LDS 9.2 KB.
__global__ __launch_bounds__(256) void k_project(
    const float* __restrict__ qf, const float* __restrict__ kf,
    const short* __restrict__ wq, const short* __restrict__ wk,
    const float* __restrict__ bq, const float* __restrict__ bk,
    short* __restrict__ outq, short* __restrict__ outk) {
    int z = blockIdx.z;
    const float* x = z ? kf : qf;
    const short* wbf = z ? wk : wq;
    const float* bias = z ? bk : bq;
    short* outT = z ? outk : outq;

    int b = blockIdx.y;
    int n0 = blockIdx.x * 32;
    int t = threadIdx.x;
    int lane = t & 63, wv = t >> 6;
    int l15 = lane & 15, q4 = lane >> 4;
    const float* xb = x + (size_t)b * C_ * N_;

    __shared__ float xs[2][32][36];  // 32 c-rows x 32 n (+pad 4)

    f32x4 acc[2][2];  // [rf][cfi]
#pragma unroll
    for (int rf = 0; rf < 2; rf++)
#pragma unroll
        for (int cfi = 0; cfi < 2; cfi++) acc[rf][cfi] = (f32x4){0.f, 0.f, 0.f, 0.f};

    int sr = t >> 3, sc = t & 7;  // stage: 32 rows x 8 f32x4
    *(f32x4*)(&xs[0][sr][sc * 4]) = *(const f32x4*)(xb + (size_t)sr * N_ + n0 + sc * 4);

    for (int ks = 0; ks < 8; ks++) {
        __syncthreads();
        int buf = ks & 1;
        if (ks < 7) {
            int cb = (ks + 1) * 32;
            *(f32x4*)(&xs[buf ^ 1][sr][sc * 4]) =
                *(const f32x4*)(xb + (size_t)(cb + sr) * N_ + n0 + sc * 4);
        }
        int cbase = ks * 32 + q4 * 8;
        bf16x8 a[2];
#pragma unroll
        for (int rf = 0; rf < 2; rf++)
#pragma unroll
            for (int j = 0; j < 8; j++) a[rf][j] = f2bf(xs[buf][q4 * 8 + j][rf * 16 + l15]);
#pragma unroll
        for (int cfi = 0; cfi < 2; cfi++) {
            int cf = wv * 2 + cfi;
            bf16x8 bfr = *(const bf16x8*)(wbf + (size_t)(cf * 16 + l15) * C_ + cbase);
#pragma unroll
            for (int rf = 0; rf < 2; rf++)
                acc[rf][cfi] = __builtin_amdgcn_mfma_f32_16x16x32_bf16(a[rf], bfr, acc[rf][cfi], 0, 0, 0);
        }
    }
    // Epilogue: D row = q4*4 + r (n within 16), col = l15 (ic within 16)
#pragma unroll
    for (int cfi = 0; cfi < 2; cfi++) {
        int ic = (wv * 2 + cfi) * 16 + l15;
        float bv = bias[ic];
#pragma unroll
        for (int rf = 0; rf < 2; rf++) {
#pragma unroll
            for (int r = 0; r < 4; r++) {
                int n = n0 + rf * 16 + q4 * 4 + r;
                outT[((size_t)b * N_ + n) * IC_ + ic] = f2bf(acc[rf][cfi][r] + bv);
            }
        }
    }
}

// ---------------- K2: correlation + partial row-max (MFMA), 2x2 wave split ----
// Block: 128 i x 512 j (JC=8). Waves: (ih, jh) = (w&1, w>>1); each wave owns
// 64 i-rows (A in regs) x 32 j of the dbuf 64-j tile -> B-reads halved.
__global__ __launch_bounds__(256, 4) void k_corr(const short* __restrict__ thetaT,
                                                 const short* __restrict__ phiT,
                                                 float* __restrict__ simp) {
    __shared__ short ph[2][64][136];  // double-buffered 64 j x 128 ic (+8 pad)
    __shared__ float red[2][128];     // cross-jh max combine

    int b = blockIdx.z, jc = blockIdx.y;
    int i0 = blockIdx.x * 128;
    int t = threadIdx.x;
    int lane = t & 63, w = t >> 6;
    int ih = w & 1, jh = w >> 1;
    int l15 = lane & 15, q4 = lane >> 4;

    const short* thb = thetaT + ((size_t)b * N_ + i0 + ih * 64) * IC_;
    const short* phb = phiT + ((size_t)b * N_ + jc * (N_ / JC_)) * IC_;

    // A-fragments: 64 i-rows per wave, K=128 (64 VGPRs)
    bf16x8 afr[4][4];
#pragma unroll
    for (int rf = 0; rf < 4; rf++)
#pragma unroll
        for (int ks = 0; ks < 4; ks++)
            afr[rf][ks] = *(const bf16x8*)(thb + (size_t)(rf * 16 + l15) * IC_ + ks * 32 + q4 * 8);

    int srow = t >> 4, sc8 = t & 15;
#pragma unroll
    for (int k = 0; k < 4; k++)
        *(bf16x8*)(&ph[0][srow + k * 16][sc8 * 8]) =
            *(const bf16x8*)(phb + (size_t)(srow + k * 16) * IC_ + sc8 * 8);

    f32x4 rmax[4];
#pragma unroll
    for (int rf = 0; rf < 4; rf++) rmax[rf] = (f32x4){-3.0e38f, -3.0e38f, -3.0e38f, -3.0e38f};

    const int NT = (N_ / JC_) / 64;  // 8 tiles
    for (int it = 0; it < NT; it++) {
        int buf = it & 1;
        __syncthreads();
        if (it < NT - 1) {
            int j0 = (it + 1) * 64;
#pragma unroll
            for (int k = 0; k < 4; k++)
                *(bf16x8*)(&ph[buf ^ 1][srow + k * 16][sc8 * 8]) =
                    *(const bf16x8*)(phb + (size_t)(j0 + srow + k * 16) * IC_ + sc8 * 8);
        }
#pragma unroll
        for (int jf2 = 0; jf2 < 2; jf2++) {
            bf16x8 bfr[4];
#pragma unroll
            for (int ks = 0; ks < 4; ks++)
                bfr[ks] = *(const bf16x8*)(&ph[buf][jh * 32 + jf2 * 16 + l15][ks * 32 + q4 * 8]);
#pragma unroll
            for (int rf = 0; rf < 4; rf++) {
                f32x4 a2 = (f32x4){0.f, 0.f, 0.f, 0.f};
#pragma unroll
                for (int ks = 0; ks < 4; ks++)
                    a2 = __builtin_amdgcn_mfma_f32_16x16x32_bf16(afr[rf][ks], bfr[ks], a2, 0, 0, 0);
#pragma unroll
                for (int r = 0; r < 4; r++) rmax[rf][r] = fmaxf(rmax[rf][r], a2[r]);
            }
        }
    }

    // reduce across the 16 j-column lanes (within this wave's j-half)
#pragma unroll
    for (int rf = 0; rf < 4; rf++) {
#pragma unroll
        for (int r = 0; r < 4; r++) {
            float v = rmax[rf][r];
            v = fmaxf(v, __shfl_xor(v, 1));
            v = fmaxf(v, __shfl_xor(v, 2));
            v = fmaxf(v, __shfl_xor(v, 4));
            v = fmaxf(v, __shfl_xor(v, 8));
            rmax[rf][r] = v;
        }
    }
    __syncthreads();  // ph no longer needed; red combine
    if (l15 == 0) {
#pragma unroll
        for (int rf = 0; rf < 4; rf++)
#pragma unroll
            for (int r = 0; r < 4; r++)
                red[jh][ih * 64 + rf * 16 + q4 * 4 + r] = rmax[rf][r];
    }
    __syncthreads();
    if (t < 128) {
        simp[((size_t)(b * JC_ + jc)) * N_ + i0 + t] = fmaxf(red[0][t], red[1][t]);
    }
}

// ---------------- K3: conv_in 1 -> 32, reflect pad; fuses 8-way partial max ----
__global__ __launch_bounds__(256) void k_conv_in(const float* __restrict__ simp,
                                                 const float* __restrict__ w,
                                                 const float* __restrict__ bias,
                                                 float* __restrict__ h) {
    int y = blockIdx.x, b = blockIdx.y;
    int t = threadIdx.x;
    int oc = t >> 3, x8 = t & 7;
    __shared__ float srow[3][66];
    const float* sb = simp + (size_t)b * JC_ * N_;
    if (t < 192) {
        int r = t >> 6, x = t & 63;
        int idx = refl(y - 1 + r) * 64 + x;
        float v = -3.0e38f;
#pragma unroll
        for (int jc = 0; jc < JC_; jc++) v = fmaxf(v, sb[jc * N_ + idx]);
        srow[r][x + 1] = v;
    }
    if (t < 3) {
        int gy = refl(y - 1 + t);
        float vl = -3.0e38f, vr = -3.0e38f;
#pragma unroll
        for (int jc = 0; jc < JC_; jc++) {
            vl = fmaxf(vl, sb[jc * N_ + gy * 64 + 1]);
            vr = fmaxf(vr, sb[jc * N_ + gy * 64 + 62]);
        }
        srow[t][0] = vl;
        srow[t][65] = vr;
    }
    __syncthreads();

    float wr[9];
#pragma unroll
    for (int k = 0; k < 9; k++) wr[k] = w[oc * 9 + k];
    float bv = bias[oc];
    float acc[8];
#pragma unroll
    for (int xi = 0; xi < 8; xi++) acc[xi] = bv;
#pragma unroll
    for (int ky = 0; ky < 3; ky++)
#pragma unroll
        for (int kx = 0; kx < 3; kx++) {
            float wv2 = wr[ky * 3 + kx];
#pragma unroll
            for (int xi = 0; xi < 8; xi++) acc[xi] += wv2 * srow[ky][x8 * 8 + xi + kx];
        }
    float* op = h + (((size_t)b * 32 + oc) * 64 + y) * 64 + x8 * 8;
#pragma unroll
    for (int xi = 0; xi < 8; xi++) op[xi] = acc[xi];
}

// ---------------- K4/K5: conv 32 -> 32, reflect pad, oc-split x2; weights in LDS ----
template <bool RELU, bool ADD>
__global__ __launch_bounds__(256) void k_conv_r(const float* __restrict__ in,
                                                const float* __restrict__ w,
                                                const float* __restrict__ bias,
                                                float* __restrict__ out,
                                                const float* __restrict__ add) {
    int y = blockIdx.x, b = blockIdx.z;
    int oc0 = blockIdx.y * 16;
    int t = threadIdx.x;
    __shared__ float tile[32][3][68];       // +1 col shift, reflect pre-applied
    __shared__ float wlds[32 * 16 * 12];    // [ic][ocl][12] (b128-aligned, conflict-free)

#pragma unroll
    for (int k = 0; k < 18; k++) {
        int id = t + k * 256;              // 0..4607
        int ocl = id / 288;
        int rem = id - ocl * 288;
        int ic = rem / 9;
        int tap = rem - ic * 9;
        wlds[(ic * 16 + ocl) * 12 + tap] = w[(size_t)(oc0 + ocl) * 288 + rem];
    }

#pragma unroll
    for (int r = 0; r < 3; r++) {
        int gy = refl(y - 1 + r);
#pragma unroll
        for (int i = 0; i < 2; i++) {
            int idx = t + i * 256;
            int ic = idx >> 4, c4 = idx & 15;
            f32x4 v = *(const f32x4*)(in + (((size_t)b * 32 + ic) * 64 + gy) * 64 + c4 * 4);
#pragma unroll
            for (int s = 0; s < 4; s++) tile[ic][r][c4 * 4 + s + 1] = v[s];
        }
    }
    if (t < 96) {
        int ic = t / 3, r = t - ic * 3;
        int gy = refl(y - 1 + r);
        const float* row = in + (((size_t)b * 32 + ic) * 64 + gy) * 64;
        tile[ic][r][0] = row[1];
        tile[ic][r][65] = row[62];
    }
    __syncthreads();

    int ocl = t >> 4, x4 = (t & 15) * 4;
    float bv = bias[oc0 + ocl];
    float acc[4];
#pragma unroll
    for (int xi = 0; xi < 4; xi++) acc[xi] = bv;

#pragma unroll 2
    for (int ic = 0; ic < 32; ic++) {
        const float* wr = &wlds[(ic * 16 + ocl) * 12];
        f32x4 W0 = *(const f32x4*)(wr);
        f32x4 W1 = *(const f32x4*)(wr + 4);
        f32x4 W2 = *(const f32x4*)(wr + 8);
        float w0 = W0[0], w1 = W0[1], w2 = W0[2], w3 = W0[3];
        float w4 = W1[0], w5 = W1[1], w6 = W1[2], w7 = W1[3];
        float w8 = W2[0];
        float xr[3][8];
#pragma unroll
        for (int r = 0; r < 3; r++) {
            const float* rowp = &tile[ic][r][x4];
            f32x4 A = *(const f32x4*)(rowp);
            f32x4 Bv = *(const f32x4*)(rowp + 4);
            xr[r][0] = A[0]; xr[r][1] = A[1]; xr[r][2] = A[2]; xr[r][3] = A[3];
            xr[r][4] = Bv[0]; xr[r][5] = Bv[1]; xr[r][6] = Bv[2]; xr[r][7] = Bv[3];
        }
#pragma unroll
        for (int xi = 0; xi < 4; xi++) {
            acc[xi] += w0 * xr[0][xi] + w1 * xr[0][xi + 1] + w2 * xr[0][xi + 2] +
                       w3 * xr[1][xi] + w4 * xr[1][xi + 1] + w5 * xr[1][xi + 2] +
                       w6 * xr[2][xi] + w7 * xr[2][xi + 1] + w8 * xr[2][xi + 2];
        }
    }
    size_t off = (((size_t)b * 32 + oc0 + ocl) * 64 + y) * 64 + x4;
#pragma unroll
    for (int xi = 0; xi < 4; xi++) {
        float v = acc[xi];
        if (RELU) v = fmaxf(v, 0.f);
        if (ADD) v += add[off + xi];
        out[off + xi] = v;
    }
}

// ---------------- K6: conv_out 32 -> 1 (ic split 4-way + LDS reduce); w in LDS ----
__global__ __launch_bounds__(256) void k_conv_out(const float* __restrict__ hb,
                                                  const float* __restrict__ w,
                                                  const float* __restrict__ bias,
                                                  float* __restrict__ outp) {
    int y = blockIdx.x, b = blockIdx.y;
    int t = threadIdx.x;
    int x = t & 63, g = t >> 6;
    __shared__ float red[4][64];
    __shared__ float wl[288];
    for (int k = t; k < 288; k += 256) wl[k] = w[k];
    __syncthreads();
    float acc = 0.f;
#pragma unroll
    for (int i = 0; i < 8; i++) {
        int ic = g * 8 + i;
        const float* wp = wl + ic * 9;
#pragma unroll
        for (int ky = 0; ky < 3; ky++) {
            int gy = refl(y + ky - 1);
            const float* row = hb + (((size_t)b * 32 + ic) * 64 + gy) * 64;
#pragma unroll
            for (int kx = 0; kx < 3; kx++) {
                int gx = refl(x + kx - 1);
                acc += wp[ky * 3 + kx] * row[gx];
            }
        }
    }
    red[g][x] = acc;
    __syncthreads();
    if (t < 64) {
        outp[((size_t)b * 64 + y) * 64 + x] =
            bias[0] + red[0][t] + red[1][t] + red[2][t] + red[3][t];
    }
}

extern "C" void kernel_launch(void* const* d_in, const int* in_sizes, int n_in,
                              void* d_out, int out_size, void* d_ws, size_t ws_size,
                              hipStream_t stream) {
    const float* q = (const float*)d_in[0];
    const float* kf = (const float*)d_in[1];
    const float* w_theta = (const float*)d_in[2];
    const float* b_theta = (const float*)d_in[3];
    const float* w_phi = (const float*)d_in[4];
    const float* b_phi = (const float*)d_in[5];
    const float* w_in = (const float*)d_in[6];
    const float* b_in = (const float*)d_in[7];
    const float* w_r1 = (const float*)d_in[8];
    const float* b_r1 = (const float*)d_in[9];
    const float* w_r2 = (const float*)d_in[10];
    const float* b_r2 = (const float*)d_in[11];
    const float* w_out = (const float*)d_in[12];
    const float* b_out = (const float*)d_in[13];
    float* out = (float*)d_out;

    char* ws = (char*)d_ws;
    short* thetaT = (short*)(ws);                 // 4 MiB (reused as h/r after k_corr)
    short* phiT = (short*)(ws + 4194304);         // 4 MiB
    short* wthb = (short*)(ws + 8388608);         // 64 KiB
    short* wphb = (short*)(ws + 8454144);         // 64 KiB
    float* simp = (float*)(ws + 8519680);         // 512 KiB [B][JC][N]
    float* h = (float*)(ws);                      // 2 MiB (over thetaT, dead by then)
    float* r = (float*)(ws + 2097152);            // 2 MiB

    k_cvt_w<<<128, 256, 0, stream>>>(w_theta, w_phi, wthb, wphb);
    k_project<<<dim3(128, 4, 2), 256, 0, stream>>>(q, kf, wthb, wphb, b_theta, b_phi,
                                                   thetaT, phiT);
    k_corr<<<dim3(32, JC_, 4), 256, 0, stream>>>(thetaT, phiT, simp);
    k_conv_in<<<dim3(64, 4), 256, 0, stream>>>(simp, w_in, b_in, h);
    k_conv_r<true, false><<<dim3(64, 2, 4), 256, 0, stream>>>(h, w_r1, b_r1, r, nullptr);
    k_conv_r<false, true><<<dim3(64, 2, 4), 256, 0, stream>>>(r, w_r2, b_r2, h, h);
    k_conv_out<<<dim3(64, 4), 256, 0, stream>>>(h, w_out, b_out, out);
}

// Round 12
// 165.316 us; speedup vs baseline: 1.1206x; 1.1206x over previous
//
#include <hip/hip_runtime.h>

#define B_ 4
#define C_ 256
#define HH 64
#define WW 64
#define N_ 4096
#define IC_ 128
#define JC_ 8   // j-split factor for correlation (R3 locality regime)

typedef __attribute__((ext_vector_type(8))) short bf16x8;
typedef __attribute__((ext_vector_type(4))) float f32x4;

__device__ __forceinline__ short f2bf(float f) {
    unsigned u = __builtin_bit_cast(unsigned, f);
    unsigned r = (u + 0x7FFFu + ((u >> 16) & 1u)) >> 16;
    return (short)r;
}

__device__ __forceinline__ int refl(int v) {
    return v < 0 ? -v : (v > 63 ? 126 - v : v);
}

// ---------------- K0: convert projection weights to bf16 ----------------
__global__ __launch_bounds__(256) void k_cvt_w(const float* __restrict__ wt,
                                               const float* __restrict__ wp,
                                               short* __restrict__ wtb,
                                               short* __restrict__ wpb) {
    int i = blockIdx.x * 256 + threadIdx.x;  // 32768 total
    wtb[i] = f2bf(wt[i]);
    wpb[i] = f2bf(wp[i]);
}

// ---------------- K1: projection GEMM (MFMA) -> thetaT/phiT [B][N][IC] bf16 ----
// n-tile 32/block, waves split ic (2 cf each): 1024 blocks = 4/CU, LDS 9.2 KB.
__global__ __launch_bounds__(256) void k_project(
    const float* __restrict__ qf, const float* __restrict__ kf,
    const short* __restrict__ wq, const short* __restrict__ wk,
    const float* __restrict__ bq, const float* __restrict__ bk,
    short* __restrict__ outq, short* __restrict__ outk) {
    int z = blockIdx.z;
    const float* x = z ? kf : qf;
    const short* wbf = z ? wk : wq;
    const float* bias = z ? bk : bq;
    short* outT = z ? outk : outq;

    int b = blockIdx.y;
    int n0 = blockIdx.x * 32;
    int t = threadIdx.x;
    int lane = t & 63, wv = t >> 6;
    int l15 = lane & 15, q4 = lane >> 4;
    const float* xb = x + (size_t)b * C_ * N_;

    __shared__ float xs[2][32][36];  // 32 c-rows x 32 n (+pad 4)

    f32x4 acc[2][2];  // [rf][cfi]
#pragma unroll
    for (int rf = 0; rf < 2; rf++)
#pragma unroll
        for (int cfi = 0; cfi < 2; cfi++) acc[rf][cfi] = (f32x4){0.f, 0.f, 0.f, 0.f};

    int sr = t >> 3, sc = t & 7;  // stage: 32 rows x 8 f32x4
    *(f32x4*)(&xs[0][sr][sc * 4]) = *(const f32x4*)(xb + (size_t)sr * N_ + n0 + sc * 4);

    for (int ks = 0; ks < 8; ks++) {
        __syncthreads();
        int buf = ks & 1;
        if (ks < 7) {
            int cb = (ks + 1) * 32;
            *(f32x4*)(&xs[buf ^ 1][sr][sc * 4]) =
                *(const f32x4*)(xb + (size_t)(cb + sr) * N_ + n0 + sc * 4);
        }
        int cbase = ks * 32 + q4 * 8;
        bf16x8 a[2];
#pragma unroll
        for (int rf = 0; rf < 2; rf++)
#pragma unroll
            for (int j = 0; j < 8; j++) a[rf][j] = f2bf(xs[buf][q4 * 8 + j][rf * 16 + l15]);
#pragma unroll
        for (int cfi = 0; cfi < 2; cfi++) {
            int cf = wv * 2 + cfi;
            bf16x8 bfr = *(const bf16x8*)(wbf + (size_t)(cf * 16 + l15) * C_ + cbase);
#pragma unroll
            for (int rf = 0; rf < 2; rf++)
                acc[rf][cfi] = __builtin_amdgcn_mfma_f32_16x16x32_bf16(a[rf], bfr, acc[rf][cfi], 0, 0, 0);
        }
    }
    // Epilogue: D row = q4*4 + r (n within 16), col = l15 (ic within 16)
#pragma unroll
    for (int cfi = 0; cfi < 2; cfi++) {
        int ic = (wv * 2 + cfi) * 16 + l15;
        float bv = bias[ic];
#pragma unroll
        for (int rf = 0; rf < 2; rf++) {
#pragma unroll
            for (int r = 0; r < 4; r++) {
                int n = n0 + rf * 16 + q4 * 4 + r;
                outT[((size_t)b * N_ + n) * IC_ + ic] = f2bf(acc[rf][cfi][r] + bv);
            }
        }
    }
}

// ---------------- K2: correlation + partial row-max (MFMA) ----------------
// JC=8 locality regime, i-tile 128/block (wave owns 32 i-rows), 1024 blocks.
__global__ __launch_bounds__(256, 4) void k_corr(const short* __restrict__ thetaT,
                                                 const short* __restrict__ phiT,
                                                 float* __restrict__ simp) {
    __shared__ short ph[2][64][136];  // double-buffered 64 j x 128 ic (+8 pad)

    int b = blockIdx.z, jc = blockIdx.y;
    int i0 = blockIdx.x * 128;
    int t = threadIdx.x;
    int lane = t & 63, w = t >> 6;
    int l15 = lane & 15, q4 = lane >> 4;

    const short* thb = thetaT + ((size_t)b * N_ + i0 + w * 32) * IC_;
    const short* phb = phiT + ((size_t)b * N_ + jc * (N_ / JC_)) * IC_;

    bf16x8 afr[2][4];
#pragma unroll
    for (int rf = 0; rf < 2; rf++)
#pragma unroll
        for (int ks = 0; ks < 4; ks++)
            afr[rf][ks] = *(const bf16x8*)(thb + (size_t)(rf * 16 + l15) * IC_ + ks * 32 + q4 * 8);

    int srow = t >> 4, sc8 = t & 15;
#pragma unroll
    for (int k = 0; k < 4; k++)
        *(bf16x8*)(&ph[0][srow + k * 16][sc8 * 8]) =
            *(const bf16x8*)(phb + (size_t)(srow + k * 16) * IC_ + sc8 * 8);

    f32x4 rmax[2];
#pragma unroll
    for (int rf = 0; rf < 2; rf++) rmax[rf] = (f32x4){-3.0e38f, -3.0e38f, -3.0e38f, -3.0e38f};

    const int NT = (N_ / JC_) / 64;  // 8 tiles
    for (int it = 0; it < NT; it++) {
        int buf = it & 1;
        __syncthreads();
        if (it < NT - 1) {
            int j0 = (it + 1) * 64;
#pragma unroll
            for (int k = 0; k < 4; k++)
                *(bf16x8*)(&ph[buf ^ 1][srow + k * 16][sc8 * 8]) =
                    *(const bf16x8*)(phb + (size_t)(j0 + srow + k * 16) * IC_ + sc8 * 8);
        }
#pragma unroll
        for (int jf = 0; jf < 4; jf++) {
            bf16x8 bfr[4];
#pragma unroll
            for (int ks = 0; ks < 4; ks++)
                bfr[ks] = *(const bf16x8*)(&ph[buf][jf * 16 + l15][ks * 32 + q4 * 8]);
#pragma unroll
            for (int rf = 0; rf < 2; rf++) {
                f32x4 a2 = (f32x4){0.f, 0.f, 0.f, 0.f};
#pragma unroll
                for (int ks = 0; ks < 4; ks++)
                    a2 = __builtin_amdgcn_mfma_f32_16x16x32_bf16(afr[rf][ks], bfr[ks], a2, 0, 0, 0);
#pragma unroll
                for (int r = 0; r < 4; r++) rmax[rf][r] = fmaxf(rmax[rf][r], a2[r]);
            }
        }
    }

#pragma unroll
    for (int rf = 0; rf < 2; rf++) {
#pragma unroll
        for (int r = 0; r < 4; r++) {
            float v = rmax[rf][r];
            v = fmaxf(v, __shfl_xor(v, 1));
            v = fmaxf(v, __shfl_xor(v, 2));
            v = fmaxf(v, __shfl_xor(v, 4));
            v = fmaxf(v, __shfl_xor(v, 8));
            rmax[rf][r] = v;
        }
    }
    if (l15 == 0) {
        float* sp = simp + ((size_t)(b * JC_ + jc)) * N_ + i0 + w * 32;
#pragma unroll
        for (int rf = 0; rf < 2; rf++)
#pragma unroll
            for (int r = 0; r < 4; r++) sp[rf * 16 + q4 * 4 + r] = rmax[rf][r];
    }
}

// ---------------- K3: conv_in 1 -> 32, reflect pad; fuses 8-way partial max ----
__global__ __launch_bounds__(256) void k_conv_in(const float* __restrict__ simp,
                                                 const float* __restrict__ w,
                                                 const float* __restrict__ bias,
                                                 float* __restrict__ h) {
    int y = blockIdx.x, b = blockIdx.y;
    int t = threadIdx.x;
    int oc = t >> 3, x8 = t & 7;
    __shared__ float srow[3][66];
    const float* sb = simp + (size_t)b * JC_ * N_;
    if (t < 192) {
        int r = t >> 6, x = t & 63;
        int idx = refl(y - 1 + r) * 64 + x;
        float v = -3.0e38f;
#pragma unroll
        for (int jc = 0; jc < JC_; jc++) v = fmaxf(v, sb[jc * N_ + idx]);
        srow[r][x + 1] = v;
    }
    if (t < 3) {
        int gy = refl(y - 1 + t);
        float vl = -3.0e38f, vr = -3.0e38f;
#pragma unroll
        for (int jc = 0; jc < JC_; jc++) {
            vl = fmaxf(vl, sb[jc * N_ + gy * 64 + 1]);
            vr = fmaxf(vr, sb[jc * N_ + gy * 64 + 62]);
        }
        srow[t][0] = vl;
        srow[t][65] = vr;
    }
    __syncthreads();

    float wr[9];
#pragma unroll
    for (int k = 0; k < 9; k++) wr[k] = w[oc * 9 + k];
    float bv = bias[oc];
    float acc[8];
#pragma unroll
    for (int xi = 0; xi < 8; xi++) acc[xi] = bv;
#pragma unroll
    for (int ky = 0; ky < 3; ky++)
#pragma unroll
        for (int kx = 0; kx < 3; kx++) {
            float wv2 = wr[ky * 3 + kx];
#pragma unroll
            for (int xi = 0; xi < 8; xi++) acc[xi] += wv2 * srow[ky][x8 * 8 + xi + kx];
        }
    float* op = h + (((size_t)b * 32 + oc) * 64 + y) * 64 + x8 * 8;
#pragma unroll
    for (int xi = 0; xi < 8; xi++) op[xi] = acc[xi];
}

// ---------------- K4/K5: conv 32 -> 32, reflect pad, oc-split x2; weights in LDS ----
template <bool RELU, bool ADD>
__global__ __launch_bounds__(256) void k_conv_r(const float* __restrict__ in,
                                                const float* __restrict__ w,
                                                const float* __restrict__ bias,
                                                float* __restrict__ out,
                                                const float* __restrict__ add) {
    int y = blockIdx.x, b = blockIdx.z;
    int oc0 = blockIdx.y * 16;
    int t = threadIdx.x;
    __shared__ float tile[32][3][68];       // +1 col shift, reflect pre-applied
    __shared__ float wlds[32 * 16 * 12];    // [ic][ocl][12] (b128-aligned, conflict-free)

#pragma unroll
    for (int k = 0; k < 18; k++) {
        int id = t + k * 256;              // 0..4607
        int ocl = id / 288;
        int rem = id - ocl * 288;
        int ic = rem / 9;
        int tap = rem - ic * 9;
        wlds[(ic * 16 + ocl) * 12 + tap] = w[(size_t)(oc0 + ocl) * 288 + rem];
    }

#pragma unroll
    for (int r = 0; r < 3; r++) {
        int gy = refl(y - 1 + r);
#pragma unroll
        for (int i = 0; i < 2; i++) {
            int idx = t + i * 256;
            int ic = idx >> 4, c4 = idx & 15;
            f32x4 v = *(const f32x4*)(in + (((size_t)b * 32 + ic) * 64 + gy) * 64 + c4 * 4);
#pragma unroll
            for (int s = 0; s < 4; s++) tile[ic][r][c4 * 4 + s + 1] = v[s];
        }
    }
    if (t < 96) {
        int ic = t / 3, r = t - ic * 3;
        int gy = refl(y - 1 + r);
        const float* row = in + (((size_t)b * 32 + ic) * 64 + gy) * 64;
        tile[ic][r][0] = row[1];
        tile[ic][r][65] = row[62];
    }
    __syncthreads();

    int ocl = t >> 4, x4 = (t & 15) * 4;
    float bv = bias[oc0 + ocl];
    float acc[4];
#pragma unroll
    for (int xi = 0; xi < 4; xi++) acc[xi] = bv;

#pragma unroll 2
    for (int ic = 0; ic < 32; ic++) {
        const float* wr = &wlds[(ic * 16 + ocl) * 12];
        f32x4 W0 = *(const f32x4*)(wr);
        f32x4 W1 = *(const f32x4*)(wr + 4);
        f32x4 W2 = *(const f32x4*)(wr + 8);
        float w0 = W0[0], w1 = W0[1], w2 = W0[2], w3 = W0[3];
        float w4 = W1[0], w5 = W1[1], w6 = W1[2], w7 = W1[3];
        float w8 = W2[0];
        float xr[3][8];
#pragma unroll
        for (int r = 0; r < 3; r++) {
            const float* rowp = &tile[ic][r][x4];
            f32x4 A = *(const f32x4*)(rowp);
            f32x4 Bv = *(const f32x4*)(rowp + 4);
            xr[r][0] = A[0]; xr[r][1] = A[1]; xr[r][2] = A[2]; xr[r][3] = A[3];
            xr[r][4] = Bv[0]; xr[r][5] = Bv[1]; xr[r][6] = Bv[2]; xr[r][7] = Bv[3];
        }
#pragma unroll
        for (int xi = 0; xi < 4; xi++) {
            acc[xi] += w0 * xr[0][xi] + w1 * xr[0][xi + 1] + w2 * xr[0][xi + 2] +
                       w3 * xr[1][xi] + w4 * xr[1][xi + 1] + w5 * xr[1][xi + 2] +
                       w6 * xr[2][xi] + w7 * xr[2][xi + 1] + w8 * xr[2][xi + 2];
        }
    }
    size_t off = (((size_t)b * 32 + oc0 + ocl) * 64 + y) * 64 + x4;
#pragma unroll
    for (int xi = 0; xi < 4; xi++) {
        float v = acc[xi];
        if (RELU) v = fmaxf(v, 0.f);
        if (ADD) v += add[off + xi];
        out[off + xi] = v;
    }
}

// ---------------- K6: conv_out 32 -> 1 (ic split 4-way + LDS reduce); w in LDS ----
__global__ __launch_bounds__(256) void k_conv_out(const float* __restrict__ hb,
                                                  const float* __restrict__ w,
                                                  const float* __restrict__ bias,
                                                  float* __restrict__ outp) {
    int y = blockIdx.x, b = blockIdx.y;
    int t = threadIdx.x;
    int x = t & 63, g = t >> 6;
    __shared__ float red[4][64];
    __shared__ float wl[288];
    for (int k = t; k < 288; k += 256) wl[k] = w[k];
    __syncthreads();
    float acc = 0.f;
#pragma unroll
    for (int i = 0; i < 8; i++) {
        int ic = g * 8 + i;
        const float* wp = wl + ic * 9;
#pragma unroll
        for (int ky = 0; ky < 3; ky++) {
            int gy = refl(y + ky - 1);
            const float* row = hb + (((size_t)b * 32 + ic) * 64 + gy) * 64;
#pragma unroll
            for (int kx = 0; kx < 3; kx++) {
                int gx = refl(x + kx - 1);
                acc += wp[ky * 3 + kx] * row[gx];
            }
        }
    }
    red[g][x] = acc;
    __syncthreads();
    if (t < 64) {
        outp[((size_t)b * 64 + y) * 64 + x] =
            bias[0] + red[0][t] + red[1][t] + red[2][t] + red[3][t];
    }
}

extern "C" void kernel_launch(void* const* d_in, const int* in_sizes, int n_in,
                              void* d_out, int out_size, void* d_ws, size_t ws_size,
                              hipStream_t stream) {
    const float* q = (const float*)d_in[0];
    const float* kf = (const float*)d_in[1];
    const float* w_theta = (const float*)d_in[2];
    const float* b_theta = (const float*)d_in[3];
    const float* w_phi = (const float*)d_in[4];
    const float* b_phi = (const float*)d_in[5];
    const float* w_in = (const float*)d_in[6];
    const float* b_in = (const float*)d_in[7];
    const float* w_r1 = (const float*)d_in[8];
    const float* b_r1 = (const float*)d_in[9];
    const float* w_r2 = (const float*)d_in[10];
    const float* b_r2 = (const float*)d_in[11];
    const float* w_out = (const float*)d_in[12];
    const float* b_out = (const float*)d_in[13];
    float* out = (float*)d_out;

    char* ws = (char*)d_ws;
    short* thetaT = (short*)(ws);                 // 4 MiB (reused as h/r after k_corr)
    short* phiT = (short*)(ws + 4194304);         // 4 MiB
    short* wthb = (short*)(ws + 8388608);         // 64 KiB
    short* wphb = (short*)(ws + 8454144);         // 64 KiB
    float* simp = (float*)(ws + 8519680);         // 512 KiB [B][JC][N]
    float* h = (float*)(ws);                      // 2 MiB (over thetaT, dead by then)
    float* r = (float*)(ws + 2097152);            // 2 MiB

    k_cvt_w<<<128, 256, 0, stream>>>(w_theta, w_phi, wthb, wphb);
    k_project<<<dim3(128, 4, 2), 256, 0, stream>>>(q, kf, wthb, wphb, b_theta, b_phi,
                                                   thetaT, phiT);
    k_corr<<<dim3(32, JC_, 4), 256, 0, stream>>>(thetaT, phiT, simp);
    k_conv_in<<<dim3(64, 4), 256, 0, stream>>>(simp, w_in, b_in, h);
    k_conv_r<true, false><<<dim3(64, 2, 4), 256, 0, stream>>>(h, w_r1, b_r1, r, nullptr);
    k_conv_r<false, true><<<dim3(64, 2, 4), 256, 0, stream>>>(r, w_r2, b_r2, h, h);
    k_conv_out<<<dim3(64, 4), 256, 0, stream>>>(h, w_out, b_out, out);
}